// Round 10
// baseline (120.510 us; speedup 1.0000x reference)
//
#include <hip/hip_runtime.h>

// OESNN_SEPhIA_MultiTiled2: 32-step recurrent SNN, B=8192.
// R11: remove ALL cross-lane LDS-pipe traffic from the t-loop. Evidence
// R2..R10: wall per 8 elems per SIMD-iter is 3000-4600 cyc across EVERY
// structure (1/2/4 waves/SIMD, prefetch depth 1/2/4, LDS or register
// weights, pinned or not) while issue varies 550-1760 -- the invariant on
// the recurrent path is the 18-shfl (ds_bpermute + lgkmcnt) pw handoff
// (or its LDS equivalent: R5's wall == 27 dependent ~120cyc ds chains).
// Fix: spikes are bits. 3x __ballot (VALU->SGPR, no LDS pipe, no lgkmcnt)
// broadcast the wave's spike predicates; each lane rebuilds
// pw_c = bit(c) ? pon_f[c] : poff_f[c] from full pon/poff tables gathered
// ONCE in the prologue (identical bits to the owners' values). Since the
// ballot predicate is exactly R2's (m2 > 0.55f) and the tables are
// bit-identical, pw_c == R2's pwall[c] bit-for-bit, and the unchanged
// ascending-c single-accumulator i1e/i1o fma chains give bit-identical
// outputs. Dup-channel bits from clamped lanes land at positions never
// read. Everything else is the verified R2/R10 structure: 8 lanes/elem,
// 1024 waves, pinned invariants under the 256-VGPR cap of (256,1),
// identical stores, select-based LIF, depth-1 x refill.

namespace {
constexpr int Tn = 32;
constexpr int Bn = 8192;
constexpr int O_PW = 0;                       // spks0 (= pw0) [T,B,18]
constexpr int O_S1 = Tn * Bn * 18;            // spks1 [T,B,8]
constexpr int O_M0 = O_S1 + Tn * Bn * 8;      // mems0 [T,B,18]
constexpr int O_M1 = O_M0 + Tn * Bn * 18;     // mems1 [T,B,8]
}

__global__ __launch_bounds__(256, 1)
void oesnn_kernel(const float* __restrict__ x_in,
                  const float* __restrict__ W0g,   // [2,18,18]
                  const float* __restrict__ d0g,   // [2,9]
                  const float* __restrict__ W1g,   // [1,18,16]
                  const float* __restrict__ d1g,   // [1,8]
                  const float* __restrict__ peakg, // [36]
                  float* __restrict__ out)
{
    const int lt  = threadIdx.x & 63;         // lane in wave
    const int tid = blockIdx.x * 256 + threadIdx.x;
    const int b   = tid >> 3;                 // batch element
    const int sub = tid & 7;                  // lane within batch group
    const int tl  = sub >> 2;                 // layer-0 tile (0/1)
    const int q   = sub & 3;                  // lane within tile
    const int j0  = (q == 0) ? 0 : (2 * q + 1);   // first in-tile channel
    const int nj  = (q == 0) ? 3 : 2;             // real channel count (pad to 3)

    // ---------------- per-lane weight preload into registers ----------------
    float w0e[3][18], w0o[3][18], dd0[3], pon[3], poff[3];
    #pragma unroll
    for (int j = 0; j < 3; ++j) {
        const int jc = (j < nj) ? (j0 + j) : j0;   // clamped dup stays in-lane
        dd0[j] = d0g[tl * 9 + jc];
        #pragma unroll
        for (int w = 0; w < 18; ++w) {
            const float2 p = *(const float2*)(W0g + ((tl * 18 + w) * 18 + 2 * jc));
            w0e[j][w] = p.x;
            w0o[j][w] = p.y;
        }
        // pw0 takes exactly two values per channel: precompute via the
        // reference's complex-division -> abs -> square path (verbatim R2).
        const int c = tl * 9 + jc;
        const float wl    = 1550.0f + 0.8f * (float)c;
        const float halfw = 0.5f * (wl * 1e3f / 15000.0f);
        const float amp   = sqrtf((exp10f(peakg[c] / 10.0f) / 1000.0f) * 1e6f);
        {   // spike = 0: lo = (0.1 + 0i)/(1 + 0i) * amp
            const float lr = 0.1f * amp;
            const float a  = sqrtf(lr * lr);
            poff[j] = a * a;
        }
        {   // spike = 1: delta = -250 / (0.5*fwhm)
            const float delta = -250.0f / halfw;
            const float den = fmaf(delta, delta, 1.0f);
            const float qr  = fmaf(delta, delta, 0.1f) / den;     // (g + d^2)/den
            const float qi  = (delta - 0.1f * delta) / den;       // (d - g*d)/den
            const float lr = qr * amp, li = qi * amp;
            const float a  = sqrtf(fmaf(lr, lr, li * li));
            pon[j] = a * a;
        }
    }

    // layer-1: lane `sub` owns output channel o = sub (columns 2o, 2o+1).
    float w1e[18], w1o[18];
    #pragma unroll
    for (int w = 0; w < 18; ++w) {
        const float2 pp = *(const float2*)(W1g + w * 16 + 2 * sub);  // 8B-aligned
        w1e[w] = pp.x;
        w1o[w] = pp.y;
    }
    const float dd1 = d1g[sub];

    const int basel = lt & ~7;

    // ---------------- prologue-only gather of full pon/poff tables ----------
    // Same owner mapping as R2's per-iter pwall gather, executed ONCE.
    // pon_f[c]/poff_f[c] are bit-identical to the owner lanes' pon/poff.
    float pon_f[18], poff_f[18];
    #pragma unroll
    for (int c = 0; c < 18; ++c) {
        const int tlc = c / 9, jc2 = c % 9;
        const int qo  = (jc2 < 3) ? 0 : ((jc2 - 1) / 2);   // owner lane-in-tile
        const int st  = (qo == 0) ? 0 : (2 * qo + 1);
        const int r   = jc2 - st;                          // owner's reg index
        pon_f[c]  = __shfl(pon[r],  basel + tlc * 4 + qo, 64);
        poff_f[c] = __shfl(poff[r], basel + tlc * 4 + qo, 64);
    }

    // ---------------- PIN all loop-invariants in VGPRs (cap = 256) ---------
    float dd1p = dd1;
    #pragma unroll
    for (int j = 0; j < 3; ++j) {
        #pragma unroll
        for (int w = 0; w < 18; ++w) {
            asm volatile("" : "+v"(w0e[j][w]));
            asm volatile("" : "+v"(w0o[j][w]));
        }
        asm volatile("" : "+v"(dd0[j]));
        asm volatile("" : "+v"(pon[j]));
        asm volatile("" : "+v"(poff[j]));
    }
    #pragma unroll
    for (int w = 0; w < 18; ++w) {
        asm volatile("" : "+v"(w1e[w]));
        asm volatile("" : "+v"(w1o[w]));
        asm volatile("" : "+v"(pon_f[w]));
        asm volatile("" : "+v"(poff_f[w]));
    }
    asm volatile("" : "+v"(dd1p));

    // ---------------- state & pointers ----------------
    float mem0[3] = {0.f, 0.f, 0.f};
    float mem1 = 0.f;

    const float* xp = x_in + (size_t)b * 36 + tl * 18;
    float* opw = out + O_PW + (size_t)b * 18 + tl * 9 + j0;
    float* om0 = out + O_M0 + (size_t)b * 18 + tl * 9 + j0;
    float* os1 = out + O_S1 + (size_t)b * 8 + sub;
    float* om1 = out + O_M1 + (size_t)b * 8 + sub;

    // prefetch t=0 inputs (18 floats = 9x float2, 8B-aligned)
    float2 xv[9];
    #pragma unroll
    for (int k = 0; k < 9; ++k) xv[k] = *(const float2*)(xp + 2 * k);

    #pragma unroll 1
    for (int t = 0; t < Tn; ++t) {
        // unpack current x, scale to optical power (reference: p_in = x * 1e-4)
        float p[18];
        #pragma unroll
        for (int k = 0; k < 9; ++k) {
            p[2 * k]     = xv[k].x * 1e-4f;
            p[2 * k + 1] = xv[k].y * 1e-4f;
        }
        // prefetch next timestep while computing this one
        xp += Bn * 36;
        if (t < Tn - 1) {
            #pragma unroll
            for (int k = 0; k < 9; ++k) xv[k] = *(const float2*)(xp + 2 * k);
        }

        // ---- layer 0: even/odd dots, balanced PD, LIF, spike predicate ----
        float pwv[3];
        int   spk[3];
        #pragma unroll
        for (int j = 0; j < 3; ++j) {
            float se = 0.f, so = 0.f;
            #pragma unroll
            for (int w = 0; w < 18; ++w) {
                se = fmaf(p[w], w0e[j][w], se);
                so = fmaf(p[w], w0o[j][w], so);
            }
            const float c0 = (se - so) * dd0[j];
            const float m  = mem0[j];
            const float m2 = (m > 0.55f) ? 0.0f : fmaf(0.95f, m, c0);
            mem0[j] = m2;
            spk[j]  = (m2 > 0.55f) ? 1 : 0;
            pwv[j]  = spk[j] ? pon[j] : poff[j];
        }

        // store pw0 / mem0 (guard the dup channel on 2-channel lanes)
        #pragma unroll
        for (int j = 0; j < 3; ++j) {
            if (j < nj) {
                opw[j] = pwv[j];
                om0[j] = mem0[j];
            }
        }

        // ---- spike broadcast via ballot: no LDS pipe, no lgkmcnt ----
        unsigned long long bm0 = __ballot(spk[0]);
        unsigned long long bm1 = __ballot(spk[1]);
        unsigned long long bm2 = __ballot(spk[2]);
        // this element's 8 relevant bits of each mask, aligned to bit 0
        const unsigned int g0 = (unsigned int)(bm0 >> basel);
        const unsigned int g1 = (unsigned int)(bm1 >> basel);
        const unsigned int g2 = (unsigned int)(bm2 >> basel);

        // ---- layer 1: rebuild pw_c from bits + tables (bit-identical to
        // R2's pwall[c]), ascending-c single-accumulator fma chains ----
        float i1e = 0.f, i1o = 0.f;
        #pragma unroll
        for (int c = 0; c < 18; ++c) {
            const int tlc = c / 9, jc2 = c % 9;
            const int qo  = (jc2 < 3) ? 0 : ((jc2 - 1) / 2);   // owner lane-in-tile
            const int st  = (qo == 0) ? 0 : (2 * qo + 1);
            const int r   = jc2 - st;                          // owner's reg index
            const unsigned int gm = (r == 0) ? g0 : ((r == 1) ? g1 : g2);
            const float pwc = ((gm >> (tlc * 4 + qo)) & 1u) ? pon_f[c] : poff_f[c];
            i1e = fmaf(pwc, w1e[c], i1e);
            i1o = fmaf(pwc, w1o[c], i1o);
        }

        const float c1 = (i1e - i1o) * dd1p;
        const float m  = mem1;
        const float m2 = (m > 0.25f) ? 0.0f : fmaf(0.95f, m, c1);
        mem1 = m2;
        *os1 = (m2 > 0.25f) ? 1.0f : 0.0f;   // 64 lanes -> 64 consecutive dwords
        *om1 = m2;

        opw += Bn * 18;
        om0 += Bn * 18;
        os1 += Bn * 8;
        om1 += Bn * 8;
    }
}

extern "C" void kernel_launch(void* const* d_in, const int* in_sizes, int n_in,
                              void* d_out, int out_size, void* d_ws, size_t ws_size,
                              hipStream_t stream) {
    (void)in_sizes; (void)n_in; (void)out_size; (void)d_ws; (void)ws_size;
    const float* x  = (const float*)d_in[0];
    const float* W0 = (const float*)d_in[1];
    const float* d0 = (const float*)d_in[2];
    const float* W1 = (const float*)d_in[3];
    const float* d1 = (const float*)d_in[4];
    const float* pk = (const float*)d_in[5];
    float* out = (float*)d_out;

    dim3 grid(Bn * 8 / 256), block(256);   // 65536 threads = 1024 waves
    hipLaunchKernelGGL(oesnn_kernel, grid, block, 0, stream,
                       x, W0, d0, W1, d1, pk, out);
}